// Round 1
// baseline (803.672 us; speedup 1.0000x reference)
//
#include <hip/hip_runtime.h>
#include <hip/hip_bf16.h>
#include <math.h>

#define EXP_E 8
#define NCLS 1000
#define DFEAT 59
#define EPSF 1e-8f
#define LN_EPSF 1e-5f

__device__ __forceinline__ float wave_allsum(float v) {
#pragma unroll
  for (int m = 32; m; m >>= 1) v += __shfl_xor(v, m, 64);
  return v;
}

// all-reduce within 32-lane halves (xor masks <= 16 stay inside each half)
__device__ __forceinline__ float half_allsum(float v) {
#pragma unroll
  for (int m = 16; m; m >>= 1) v += __shfl_xor(v, m, 64);
  return v;
}

// ---------------- Kernel 1: feature extraction ----------------
// one block (256 thr) per batch row; 8 experts x 1000 classes staged in LDS
__global__ __launch_bounds__(256) void feat_kernel(const float* __restrict__ post,
                                                   float* __restrict__ fout) {
  __shared__ float sp[EXP_E * NCLS];   // 32000 B
  __shared__ float smp[NCLS];          // mean over experts
  __shared__ float slmp[NCLS];         // log(mean_p + eps)
  __shared__ float sred[12];
  __shared__ float sfeat[DFEAT];

  const int tid = threadIdx.x;
  const int b = blockIdx.x;
  const float* pb = post + (size_t)b * (EXP_E * NCLS);

  // stage 8000 floats = 2000 float4, coalesced
  const float4* pb4 = reinterpret_cast<const float4*>(pb);
  float4* sp4 = reinterpret_cast<float4*>(sp);
  for (int i = tid; i < (EXP_E * NCLS) / 4; i += 256) sp4[i] = pb4[i];
  __syncthreads();

  // ---- pass A: per-class cross-expert stats ----
  float a_ment = 0.f, a_mvar = 0.f, a_mn2 = 0.f;
  for (int c = tid; c < NCLS; c += 256) {
    float v[EXP_E];
    float s1 = 0.f;
#pragma unroll
    for (int e = 0; e < EXP_E; ++e) { v[e] = sp[e * NCLS + c]; s1 += v[e]; }
    float mp = s1 * 0.125f;
    float q = 0.f;
#pragma unroll
    for (int e = 0; e < EXP_E; ++e) { float d = v[e] - mp; q += d * d; }
    a_mvar += q * (1.f / 7.f);            // ddof=1 variance across experts
    float lmp = __logf(mp + EPSF);
    smp[c] = mp;
    slmp[c] = lmp;
    a_ment += mp * lmp;
    a_mn2 += mp * mp;
  }
  a_ment = wave_allsum(a_ment);
  a_mvar = wave_allsum(a_mvar);
  a_mn2 = wave_allsum(a_mn2);
  const int wv = tid >> 6;
  if ((tid & 63) == 0) {
    sred[wv * 3 + 0] = a_ment;
    sred[wv * 3 + 1] = a_mvar;
    sred[wv * 3 + 2] = a_mn2;
  }
  __syncthreads();  // also publishes smp/slmp
  const float s_ment = sred[0] + sred[3] + sred[6] + sred[9];
  const float s_mvar = sred[1] + sred[4] + sred[7] + sred[10];
  const float s_mn2  = sred[2] + sred[5] + sred[8] + sred[11];
  const float mn = fmaxf(sqrtf(s_mn2), EPSF);

  // ---- pass B: per-expert stats; 32 lanes per expert ----
  const int e = tid >> 5;
  const int l32 = tid & 31;
  float ent = 0.f, sq = 0.f, dot = 0.f, kl = 0.f;
  float t0 = -1.f, t1 = -1.f, t2 = -1.f, t3 = -1.f, t4 = -1.f;  // probs > 0
  for (int c = l32; c < NCLS; c += 32) {
    float p = sp[e * NCLS + c];
    float lp = __logf(p + EPSF);
    ent += p * lp;
    sq += p * p;
    dot += p * smp[c];
    kl += p * (lp - slmp[c]);
    // branchless sorted insert (descending t0..t4)
    float x = p, m;
    m = fmaxf(t0, x); x = fminf(t0, x); t0 = m;
    m = fmaxf(t1, x); x = fminf(t1, x); t1 = m;
    m = fmaxf(t2, x); x = fminf(t2, x); t2 = m;
    m = fmaxf(t3, x); x = fminf(t3, x); t3 = m;
    t4 = fmaxf(t4, x);
  }
  ent = half_allsum(ent);
  sq  = half_allsum(sq);
  dot = half_allsum(dot);
  kl  = half_allsum(kl);
  // butterfly merge of per-lane sorted top-5 lists across the 32-lane group
#pragma unroll
  for (int m = 1; m <= 16; m <<= 1) {
    float o0 = __shfl_xor(t0, m, 64), o1 = __shfl_xor(t1, m, 64), o2 = __shfl_xor(t2, m, 64),
          o3 = __shfl_xor(t3, m, 64), o4 = __shfl_xor(t4, m, 64);
    float r0 = fmaxf(t0, o0);
    float r1 = fmaxf(fmaxf(t1, o1), fminf(t0, o0));
    float r2 = fmaxf(fmaxf(t2, o2), fmaxf(fminf(t1, o0), fminf(t0, o1)));
    float r3 = fmaxf(fmaxf(t3, o3),
                     fmaxf(fminf(t2, o0), fmaxf(fminf(t1, o1), fminf(t0, o2))));
    float r4 = fmaxf(fmaxf(t4, o4),
                     fmaxf(fmaxf(fminf(t3, o0), fminf(t2, o1)),
                           fmaxf(fminf(t1, o2), fminf(t0, o3))));
    t0 = r0; t1 = r1; t2 = r2; t3 = r3; t4 = r4;
  }

  if (l32 == 0) {
    float mass = t0 + t1 + t2 + t3 + t4;
    float pn = fmaxf(sqrtf(sq), EPSF);
    sfeat[0 * 8 + e] = -ent;           // entropy
    sfeat[1 * 8 + e] = mass;           // topk_mass
    sfeat[2 * 8 + e] = 1.f - mass;     // residual
    sfeat[3 * 8 + e] = t0;             // max_probs
    sfeat[4 * 8 + e] = t0 - t1;        // top_gap
    sfeat[5 * 8 + e] = dot / (pn * mn);// cos
    sfeat[6 * 8 + e] = kl;             // kl
  }
  __syncthreads();
  if (tid == 0) {
    float s = 0.f;
#pragma unroll
    for (int i = 0; i < 8; ++i) s += sfeat[24 + i];
    float mu = s * 0.125f;
    float q = 0.f;
#pragma unroll
    for (int i = 0; i < 8; ++i) { float d = sfeat[24 + i] - mu; q += d * d; }
    sfeat[56] = -s_ment;                       // mean_ent
    sfeat[57] = s_mvar * (1.f / (float)NCLS);  // mean_class_var
    sfeat[58] = sqrtf(q * (1.f / 7.f));        // std_max (ddof=1)
  }
  __syncthreads();
  if (tid < DFEAT) {
    float v = sfeat[tid];
    v = fminf(fmaxf(v, -100.f), 100.f);
    fout[(size_t)b * DFEAT + tid] = v;
  }
}

// ---------------- Kernel 2: MLP head ----------------
// one block (256 thr) per 32 rows; register-tiled GEMV so each weight is
// loaded once per 32 rows (weight L2 traffic ~100 MB total).
__global__ __launch_bounds__(256) void mlp_kernel(
    const float* __restrict__ feats,
    const float* __restrict__ W1, const float* __restrict__ b1,
    const float* __restrict__ g1, const float* __restrict__ be1,
    const float* __restrict__ W2, const float* __restrict__ b2,
    const float* __restrict__ g2, const float* __restrict__ be2,
    const float* __restrict__ W3, const float* __restrict__ b3,
    float* __restrict__ out_w, float* __restrict__ out_l) {
  __shared__ float sfe[32 * DFEAT];   // 7552 B
  __shared__ float h1[32 * 256];      // 32768 B
  __shared__ float h2[32 * 132];      // 16896 B (stride 132 breaks bank alias)
  __shared__ float sW3[128 * 8];      // 4096 B

  const int tid = threadIdx.x;
  const int r0 = blockIdx.x * 32;

  for (int i = tid; i < 32 * DFEAT; i += 256) sfe[i] = feats[(size_t)r0 * DFEAT + i];
  for (int i = tid; i < 128 * 8; i += 256) sW3[i] = W3[i];
  __syncthreads();

  // layer 1: thread owns column tid, accumulates 32 rows
  float acc[32];
#pragma unroll
  for (int r = 0; r < 32; ++r) acc[r] = 0.f;
  for (int k = 0; k < DFEAT; ++k) {
    float w = W1[k * 256 + tid];
#pragma unroll
    for (int r = 0; r < 32; ++r) acc[r] += sfe[r * DFEAT + k] * w;  // LDS broadcast
  }
  {
    float bb = b1[tid];
#pragma unroll
    for (int r = 0; r < 32; ++r) h1[r * 256 + tid] = acc[r] + bb;
  }
  __syncthreads();

  // LN1 + relu: wave handles 8 rows, two-pass (mean, then var)
  const int wvi = tid >> 6, ln = tid & 63;
  for (int rr = 0; rr < 8; ++rr) {
    int r = wvi * 8 + rr;
    float x0 = h1[r * 256 + ln],        x1 = h1[r * 256 + ln + 64];
    float x2 = h1[r * 256 + ln + 128],  x3 = h1[r * 256 + ln + 192];
    float s = wave_allsum(x0 + x1 + x2 + x3);
    float mu = s * (1.f / 256.f);
    float d0 = x0 - mu, d1 = x1 - mu, d2 = x2 - mu, d3 = x3 - mu;
    float q = wave_allsum(d0 * d0 + d1 * d1 + d2 * d2 + d3 * d3);
    float inv = 1.0f / sqrtf(q * (1.f / 256.f) + LN_EPSF);
    h1[r * 256 + ln]       = fmaxf(d0 * inv * g1[ln]       + be1[ln],       0.f);
    h1[r * 256 + ln + 64]  = fmaxf(d1 * inv * g1[ln + 64]  + be1[ln + 64],  0.f);
    h1[r * 256 + ln + 128] = fmaxf(d2 * inv * g1[ln + 128] + be1[ln + 128], 0.f);
    h1[r * 256 + ln + 192] = fmaxf(d3 * inv * g1[ln + 192] + be1[ln + 192], 0.f);
  }
  __syncthreads();

  // layer 2: 128 cols x 2 row-halves; thread owns (col, 16 rows)
  const int j2 = tid & 127, rh = tid >> 7;
  float a2[16];
#pragma unroll
  for (int r = 0; r < 16; ++r) a2[r] = 0.f;
  for (int k = 0; k < 256; ++k) {
    float w = W2[k * 128 + j2];
#pragma unroll
    for (int r = 0; r < 16; ++r) a2[r] += h1[(rh * 16 + r) * 256 + k] * w;
  }
  {
    float bb = b2[j2];
#pragma unroll
    for (int r = 0; r < 16; ++r) h2[(rh * 16 + r) * 132 + j2] = a2[r] + bb;
  }
  __syncthreads();

  // LN2 + relu over 128 cols
  for (int rr = 0; rr < 8; ++rr) {
    int r = wvi * 8 + rr;
    float x0 = h2[r * 132 + ln], x1 = h2[r * 132 + ln + 64];
    float s = wave_allsum(x0 + x1);
    float mu = s * (1.f / 128.f);
    float d0 = x0 - mu, d1 = x1 - mu;
    float q = wave_allsum(d0 * d0 + d1 * d1);
    float inv = 1.0f / sqrtf(q * (1.f / 128.f) + LN_EPSF);
    h2[r * 132 + ln]      = fmaxf(d0 * inv * g2[ln]      + be2[ln],      0.f);
    h2[r * 132 + ln + 64] = fmaxf(d1 * inv * g2[ln + 64] + be2[ln + 64], 0.f);
  }
  __syncthreads();

  // layer 3 + softmax: thread = (row, expert)
  {
    const int r = tid >> 3, e = tid & 7;
    float s = b3[e];
    for (int k = 0; k < 128; ++k) s += h2[r * 132 + k] * sW3[k * 8 + e];
    float m = s;
#pragma unroll
    for (int mk = 4; mk; mk >>= 1) m = fmaxf(m, __shfl_xor(m, mk, 64));
    float ex = __expf(s - m);
    float den = ex;
#pragma unroll
    for (int mk = 4; mk; mk >>= 1) den += __shfl_xor(den, mk, 64);
    out_l[(size_t)(r0 + r) * 8 + e] = s;
    out_w[(size_t)(r0 + r) * 8 + e] = ex / den;
  }
}

extern "C" void kernel_launch(void* const* d_in, const int* in_sizes, int n_in,
                              void* d_out, int out_size, void* d_ws, size_t ws_size,
                              hipStream_t stream) {
  const float* post = (const float*)d_in[0];
  const float* W1  = (const float*)d_in[1];
  const float* b1  = (const float*)d_in[2];
  const float* g1  = (const float*)d_in[3];
  const float* be1 = (const float*)d_in[4];
  const float* W2  = (const float*)d_in[5];
  const float* b2  = (const float*)d_in[6];
  const float* g2  = (const float*)d_in[7];
  const float* be2 = (const float*)d_in[8];
  const float* W3  = (const float*)d_in[9];
  const float* b3  = (const float*)d_in[10];

  float* out = (float*)d_out;
  const int B = in_sizes[0] / (EXP_E * NCLS);  // 16384

  float* out_w = out;                       // weights (B,8)
  float* out_l = out + (size_t)B * 8;       // logits  (B,8)
  float* fout  = out + (size_t)2 * B * 8;   // feats   (B,59)

  hipLaunchKernelGGL(feat_kernel, dim3(B), dim3(256), 0, stream, post, fout);
  hipLaunchKernelGGL(mlp_kernel, dim3(B / 32), dim3(256), 0, stream,
                     fout, W1, b1, g1, be1, W2, b2, g2, be2, W3, b3, out_w, out_l);
}

// Round 2
// 780.355 us; speedup vs baseline: 1.0299x; 1.0299x over previous
//
#include <hip/hip_runtime.h>
#include <hip/hip_bf16.h>
#include <math.h>

#define EXP_E 8
#define NCLS 1000
#define DFEAT 59
#define EPSF 1e-8f
#define LN_EPSF 1e-5f

__device__ __forceinline__ float wave_allsum(float v) {
#pragma unroll
  for (int m = 32; m; m >>= 1) v += __shfl_xor(v, m, 64);
  return v;
}

// all-reduce within 32-lane halves (xor masks <= 16 stay inside each half)
__device__ __forceinline__ float half_allsum(float v) {
#pragma unroll
  for (int m = 16; m; m >>= 1) v += __shfl_xor(v, m, 64);
  return v;
}

// branchless sorted insert (descending t0..t4); probs are > 0, init -1
#define INS5(px)                                            \
  {                                                         \
    float x_ = (px), m_;                                    \
    m_ = fmaxf(t0, x_); x_ = fminf(t0, x_); t0 = m_;        \
    m_ = fmaxf(t1, x_); x_ = fminf(t1, x_); t1 = m_;        \
    m_ = fmaxf(t2, x_); x_ = fminf(t2, x_); t2 = m_;        \
    m_ = fmaxf(t3, x_); x_ = fminf(t3, x_); t3 = m_;        \
    t4 = fmaxf(t4, x_);                                     \
  }

#define ACCUM(pv, mv, lmv)                                  \
  {                                                         \
    float p_ = (pv);                                        \
    float lp_ = __logf(p_ + EPSF);                          \
    ent += p_ * lp_;                                        \
    sq += p_ * p_;                                          \
    dot += p_ * (mv);                                       \
    kl += p_ * (lp_ - (lmv));                               \
    INS5(p_);                                               \
  }

// ---------------- Kernel 1: feature extraction ----------------
// one block (256 thr) per batch row; 8 experts x 1000 classes staged in LDS
__global__ __launch_bounds__(256) void feat_kernel(const float* __restrict__ post,
                                                   float* __restrict__ fout) {
  __shared__ float sp[EXP_E * NCLS];   // 32000 B
  __shared__ float smp[NCLS];          // mean over experts
  __shared__ float slmp[NCLS];         // log(mean_p + eps)
  __shared__ float sred[12];
  __shared__ float sfeat[DFEAT];

  const int tid = threadIdx.x;
  const int b = blockIdx.x;
  const float* pb = post + (size_t)b * (EXP_E * NCLS);

  // stage 8000 floats = 2000 float4, coalesced
  const float4* pb4 = reinterpret_cast<const float4*>(pb);
  float4* sp4 = reinterpret_cast<float4*>(sp);
  for (int i = tid; i < (EXP_E * NCLS) / 4; i += 256) sp4[i] = pb4[i];
  __syncthreads();

  // ---- pass A: per-class cross-expert stats, 4 classes/thread via b128 ----
  float a_ment = 0.f, a_mvar = 0.f, a_mn2 = 0.f;
  if (tid < 250) {
    const int c4 = tid * 4;  // word offset, 16B-aligned (c4*4 % 16 == 0)
    float vv[EXP_E][4];
#pragma unroll
    for (int e2 = 0; e2 < EXP_E; ++e2) {
      float4 t = *reinterpret_cast<const float4*>(sp + e2 * NCLS + c4);
      vv[e2][0] = t.x; vv[e2][1] = t.y; vv[e2][2] = t.z; vv[e2][3] = t.w;
    }
    float mpv[4], lmv[4];
#pragma unroll
    for (int j = 0; j < 4; ++j) {
      float s1 = 0.f;
#pragma unroll
      for (int e2 = 0; e2 < EXP_E; ++e2) s1 += vv[e2][j];
      float mp = s1 * 0.125f;
      float q = 0.f;
#pragma unroll
      for (int e2 = 0; e2 < EXP_E; ++e2) { float d = vv[e2][j] - mp; q += d * d; }
      a_mvar += q * (1.f / 7.f);  // ddof=1 variance across experts
      float lmp = __logf(mp + EPSF);
      mpv[j] = mp; lmv[j] = lmp;
      a_ment += mp * lmp;
      a_mn2 += mp * mp;
    }
    *reinterpret_cast<float4*>(smp + c4)  = make_float4(mpv[0], mpv[1], mpv[2], mpv[3]);
    *reinterpret_cast<float4*>(slmp + c4) = make_float4(lmv[0], lmv[1], lmv[2], lmv[3]);
  }
  a_ment = wave_allsum(a_ment);
  a_mvar = wave_allsum(a_mvar);
  a_mn2 = wave_allsum(a_mn2);
  const int wv = tid >> 6;
  if ((tid & 63) == 0) {
    sred[wv * 3 + 0] = a_ment;
    sred[wv * 3 + 1] = a_mvar;
    sred[wv * 3 + 2] = a_mn2;
  }
  __syncthreads();  // also publishes smp/slmp
  const float s_ment = sred[0] + sred[3] + sred[6] + sred[9];
  const float s_mvar = sred[1] + sred[4] + sred[7] + sred[10];
  const float s_mn2  = sred[2] + sred[5] + sred[8] + sred[11];
  const float mn = fmaxf(sqrtf(s_mn2), EPSF);

  // ---- pass B: per-expert stats; 32 lanes per expert, 4 classes per iter ----
  const int e = tid >> 5;
  const int l32 = tid & 31;
  float ent = 0.f, sq = 0.f, dot = 0.f, kl = 0.f;
  float t0 = -1.f, t1 = -1.f, t2 = -1.f, t3 = -1.f, t4 = -1.f;
  const float4* spe4 = reinterpret_cast<const float4*>(sp + e * NCLS);
  const float4* smp4 = reinterpret_cast<const float4*>(smp);
  const float4* slm4 = reinterpret_cast<const float4*>(slmp);
  for (int k = l32; k < 250; k += 32) {  // tail (k=224+l32) active for l32<26
    float4 p4 = spe4[k];
    float4 m4 = smp4[k];
    float4 l4 = slm4[k];
    ACCUM(p4.x, m4.x, l4.x);
    ACCUM(p4.y, m4.y, l4.y);
    ACCUM(p4.z, m4.z, l4.z);
    ACCUM(p4.w, m4.w, l4.w);
  }
  ent = half_allsum(ent);
  sq  = half_allsum(sq);
  dot = half_allsum(dot);
  kl  = half_allsum(kl);
  // butterfly merge of per-lane sorted top-5 lists across the 32-lane group
#pragma unroll
  for (int m = 1; m <= 16; m <<= 1) {
    float o0 = __shfl_xor(t0, m, 64), o1 = __shfl_xor(t1, m, 64), o2 = __shfl_xor(t2, m, 64),
          o3 = __shfl_xor(t3, m, 64), o4 = __shfl_xor(t4, m, 64);
    float r0 = fmaxf(t0, o0);
    float r1 = fmaxf(fmaxf(t1, o1), fminf(t0, o0));
    float r2 = fmaxf(fmaxf(t2, o2), fmaxf(fminf(t1, o0), fminf(t0, o1)));
    float r3 = fmaxf(fmaxf(t3, o3),
                     fmaxf(fminf(t2, o0), fmaxf(fminf(t1, o1), fminf(t0, o2))));
    float r4 = fmaxf(fmaxf(t4, o4),
                     fmaxf(fmaxf(fminf(t3, o0), fminf(t2, o1)),
                           fmaxf(fminf(t1, o2), fminf(t0, o3))));
    t0 = r0; t1 = r1; t2 = r2; t3 = r3; t4 = r4;
  }

  if (l32 == 0) {
    float mass = t0 + t1 + t2 + t3 + t4;
    float pn = fmaxf(sqrtf(sq), EPSF);
    sfeat[0 * 8 + e] = -ent;            // entropy
    sfeat[1 * 8 + e] = mass;            // topk_mass
    sfeat[2 * 8 + e] = 1.f - mass;      // residual
    sfeat[3 * 8 + e] = t0;              // max_probs
    sfeat[4 * 8 + e] = t0 - t1;         // top_gap
    sfeat[5 * 8 + e] = dot / (pn * mn); // cos
    sfeat[6 * 8 + e] = kl;              // kl
  }
  __syncthreads();
  if (tid == 0) {
    float s = 0.f;
#pragma unroll
    for (int i = 0; i < 8; ++i) s += sfeat[24 + i];
    float mu = s * 0.125f;
    float q = 0.f;
#pragma unroll
    for (int i = 0; i < 8; ++i) { float d = sfeat[24 + i] - mu; q += d * d; }
    sfeat[56] = -s_ment;                       // mean_ent
    sfeat[57] = s_mvar * (1.f / (float)NCLS);  // mean_class_var
    sfeat[58] = sqrtf(q * (1.f / 7.f));        // std_max (ddof=1)
  }
  __syncthreads();
  if (tid < DFEAT) {
    float v = sfeat[tid];
    v = fminf(fmaxf(v, -100.f), 100.f);
    fout[(size_t)b * DFEAT + tid] = v;
  }
}

// ---------------- Kernel 2: MLP head ----------------
// one block (256 thr) per 32 rows; register-tiled GEMV so each weight is
// loaded once per 32 rows (weight L2 traffic ~100 MB total).
__global__ __launch_bounds__(256) void mlp_kernel(
    const float* __restrict__ feats,
    const float* __restrict__ W1, const float* __restrict__ b1,
    const float* __restrict__ g1, const float* __restrict__ be1,
    const float* __restrict__ W2, const float* __restrict__ b2,
    const float* __restrict__ g2, const float* __restrict__ be2,
    const float* __restrict__ W3, const float* __restrict__ b3,
    float* __restrict__ out_w, float* __restrict__ out_l) {
  __shared__ float sfe[32 * DFEAT];   // 7552 B (32*59 floats, %4==0 -> float4 ok)
  __shared__ float h1[32 * 256];      // 32768 B
  __shared__ float h2[32 * 132];      // 16896 B (stride 132 breaks bank alias)
  __shared__ float sW3[128 * 8];      // 4096 B

  const int tid = threadIdx.x;
  const int r0 = blockIdx.x * 32;

  {
    const float4* f4 = reinterpret_cast<const float4*>(feats + (size_t)r0 * DFEAT);
    float4* s4 = reinterpret_cast<float4*>(sfe);
    for (int i = tid; i < (32 * DFEAT) / 4; i += 256) s4[i] = f4[i];
    const float4* w4 = reinterpret_cast<const float4*>(W3);
    float4* sw4 = reinterpret_cast<float4*>(sW3);
    if (tid < 256) sw4[tid] = w4[tid];
  }
  __syncthreads();

  // layer 1: thread owns column tid, accumulates 32 rows
  float acc[32];
#pragma unroll
  for (int r = 0; r < 32; ++r) acc[r] = 0.f;
  for (int k = 0; k < DFEAT; ++k) {
    float w = W1[k * 256 + tid];
#pragma unroll
    for (int r = 0; r < 32; ++r) acc[r] += sfe[r * DFEAT + k] * w;  // LDS broadcast
  }
  {
    float bb = b1[tid];
#pragma unroll
    for (int r = 0; r < 32; ++r) h1[r * 256 + tid] = acc[r] + bb;
  }
  __syncthreads();

  // LN1 + relu: wave handles 8 rows, two-pass (mean, then var)
  const int wvi = tid >> 6, ln = tid & 63;
  for (int rr = 0; rr < 8; ++rr) {
    int r = wvi * 8 + rr;
    float x0 = h1[r * 256 + ln],        x1 = h1[r * 256 + ln + 64];
    float x2 = h1[r * 256 + ln + 128],  x3 = h1[r * 256 + ln + 192];
    float s = wave_allsum(x0 + x1 + x2 + x3);
    float mu = s * (1.f / 256.f);
    float d0 = x0 - mu, d1 = x1 - mu, d2 = x2 - mu, d3 = x3 - mu;
    float q = wave_allsum(d0 * d0 + d1 * d1 + d2 * d2 + d3 * d3);
    float inv = 1.0f / sqrtf(q * (1.f / 256.f) + LN_EPSF);
    h1[r * 256 + ln]       = fmaxf(d0 * inv * g1[ln]       + be1[ln],       0.f);
    h1[r * 256 + ln + 64]  = fmaxf(d1 * inv * g1[ln + 64]  + be1[ln + 64],  0.f);
    h1[r * 256 + ln + 128] = fmaxf(d2 * inv * g1[ln + 128] + be1[ln + 128], 0.f);
    h1[r * 256 + ln + 192] = fmaxf(d3 * inv * g1[ln + 192] + be1[ln + 192], 0.f);
  }
  __syncthreads();

  // layer 2: 128 cols x 2 row-halves; thread owns (col, 16 rows)
  const int j2 = tid & 127, rh = tid >> 7;
  float a2[16];
#pragma unroll
  for (int r = 0; r < 16; ++r) a2[r] = 0.f;
  for (int k = 0; k < 256; ++k) {
    float w = W2[k * 128 + j2];
#pragma unroll
    for (int r = 0; r < 16; ++r) a2[r] += h1[(rh * 16 + r) * 256 + k] * w;
  }
  {
    float bb = b2[j2];
#pragma unroll
    for (int r = 0; r < 16; ++r) h2[(rh * 16 + r) * 132 + j2] = a2[r] + bb;
  }
  __syncthreads();

  // LN2 + relu over 128 cols
  for (int rr = 0; rr < 8; ++rr) {
    int r = wvi * 8 + rr;
    float x0 = h2[r * 132 + ln], x1 = h2[r * 132 + ln + 64];
    float s = wave_allsum(x0 + x1);
    float mu = s * (1.f / 128.f);
    float d0 = x0 - mu, d1 = x1 - mu;
    float q = wave_allsum(d0 * d0 + d1 * d1);
    float inv = 1.0f / sqrtf(q * (1.f / 128.f) + LN_EPSF);
    h2[r * 132 + ln]      = fmaxf(d0 * inv * g2[ln]      + be2[ln],      0.f);
    h2[r * 132 + ln + 64] = fmaxf(d1 * inv * g2[ln + 64] + be2[ln + 64], 0.f);
  }
  __syncthreads();

  // layer 3 + softmax: thread = (row, expert)
  {
    const int r = tid >> 3, e = tid & 7;
    float s = b3[e];
    for (int k = 0; k < 128; ++k) s += h2[r * 132 + k] * sW3[k * 8 + e];
    float m = s;
#pragma unroll
    for (int mk = 4; mk; mk >>= 1) m = fmaxf(m, __shfl_xor(m, mk, 64));
    float ex = __expf(s - m);
    float den = ex;
#pragma unroll
    for (int mk = 4; mk; mk >>= 1) den += __shfl_xor(den, mk, 64);
    out_l[(size_t)(r0 + r) * 8 + e] = s;
    out_w[(size_t)(r0 + r) * 8 + e] = ex / den;
  }
}

extern "C" void kernel_launch(void* const* d_in, const int* in_sizes, int n_in,
                              void* d_out, int out_size, void* d_ws, size_t ws_size,
                              hipStream_t stream) {
  const float* post = (const float*)d_in[0];
  const float* W1  = (const float*)d_in[1];
  const float* b1  = (const float*)d_in[2];
  const float* g1  = (const float*)d_in[3];
  const float* be1 = (const float*)d_in[4];
  const float* W2  = (const float*)d_in[5];
  const float* b2  = (const float*)d_in[6];
  const float* g2  = (const float*)d_in[7];
  const float* be2 = (const float*)d_in[8];
  const float* W3  = (const float*)d_in[9];
  const float* b3  = (const float*)d_in[10];

  float* out = (float*)d_out;
  const int B = in_sizes[0] / (EXP_E * NCLS);  // 16384

  float* out_w = out;                       // weights (B,8)
  float* out_l = out + (size_t)B * 8;       // logits  (B,8)
  float* fout  = out + (size_t)2 * B * 8;   // feats   (B,59)

  hipLaunchKernelGGL(feat_kernel, dim3(B), dim3(256), 0, stream, post, fout);
  hipLaunchKernelGGL(mlp_kernel, dim3(B / 32), dim3(256), 0, stream,
                     fout, W1, b1, g1, be1, W2, b2, g2, be2, W3, b3, out_w, out_l);
}